// Round 8
// baseline (208.495 us; speedup 1.0000x reference)
//
#include <hip/hip_runtime.h>
#include <math.h>

#define HIDDEN 4096
#define NEXP 64
#define TOPK 8
#define MARGIN 2.5e-4f
#define BK 64
#define TPB 64            // tokens per block
#define NCHUNK (HIDDEN / BK)

using short8   = __attribute__((ext_vector_type(8))) short;   // 8 bf16 fragment
using floatx4  = __attribute__((ext_vector_type(4))) float;   // MFMA acc
using ushort4v = __attribute__((ext_vector_type(4))) unsigned short;
using uint4v   = __attribute__((ext_vector_type(4))) unsigned int;

// d_ws layout: [0,4) redo counter | [64, 64+64K) redo token list |
//              [128K, 640K) W_hi bf16[64][4096] | [640K, 1152K) W_lo
#define WS_LIST_OFF (64)
#define WS_WHI_OFF  (128 * 1024)
#define WS_WLO_OFF  (640 * 1024)
#define WS_NEED     (1152 * 1024)

__device__ __forceinline__ unsigned short bf16_rn(float x) {
    unsigned int u = __builtin_bit_cast(unsigned int, x);
    unsigned int r = u + 0x7FFFu + ((u >> 16) & 1u);   // round-to-nearest-even
    return (unsigned short)(r >> 16);
}
__device__ __forceinline__ float bf16_to_f(unsigned short h) {
    unsigned int u = ((unsigned int)h) << 16;
    return __builtin_bit_cast(float, u);
}

__device__ __forceinline__ void gload16(const void* g, void* l) {
    __builtin_amdgcn_global_load_lds(
        (const __attribute__((address_space(1))) void*)g,
        (__attribute__((address_space(3))) void*)l, 16, 0, 0);
}

// ---------------- pass 0: split W into bf16 hi/lo (RN, runs every call) ----
__global__ void wconv_kernel(const float* __restrict__ W,
                             unsigned short* __restrict__ Whi,
                             unsigned short* __restrict__ Wlo,
                             int* __restrict__ cnt) {
    if (blockIdx.x == 0 && threadIdx.x == 0) *cnt = 0;
    int i = (blockIdx.x * 256 + threadIdx.x) * 4;
    float4 w = *reinterpret_cast<const float4*>(W + i);
    float ws4[4] = {w.x, w.y, w.z, w.w};
    unsigned short h[4], l[4];
#pragma unroll
    for (int j = 0; j < 4; ++j) {
        h[j] = bf16_rn(ws4[j]);
        l[j] = bf16_rn(ws4[j] - bf16_to_f(h[j]));
    }
    ushort4v hv = {h[0], h[1], h[2], h[3]};
    ushort4v lv = {l[0], l[1], l[2], l[3]};
    *reinterpret_cast<ushort4v*>(Whi + i) = hv;
    *reinterpret_cast<ushort4v*>(Wlo + i) = lv;
}

// ---------------- pass 1: MFMA gate ----------------------------------------
// 512 thr = 8 waves; block owns 64 tokens x 64 experts, K chunked by 64.
// Wave q: tt=q>>2 (32-token half), eh=(q>>1)&1 (32-expert half), kh=q&1
// (half-chunk K-split; 2-way reduce in LDS epilogue).
// LDS: 3 sets x 32 KB: X[64][64]f32 @0 (16K) | Whi[64][64]bf16 @16384 (8K)
//      | Wlo @24576 (8K). Swizzle both sides (rule #21): byte ^= (row&7)<<4.
// Staging roles: waves 0-3 X, 4-5 Whi, 6-7 Wlo; 4 gload16/thread/chunk.
// Pipeline (round-7 proven skeleton): depth-2 prefetch, wait vmcnt(4),
// one barrier per iter, never drain to 0 in the loop.

__global__ __launch_bounds__(512, 2)
void gate_mfma(const float* __restrict__ X,
               const unsigned short* __restrict__ Whi,
               const unsigned short* __restrict__ Wlo,
               float* __restrict__ out,
               int* __restrict__ redo_cnt, int* __restrict__ redo_list, int T) {
    __shared__ __align__(16) char smem[98304];   // 3 x 32 KB
    const int tid  = threadIdx.x;
    const int lane = tid & 63;
    const int q    = tid >> 6;              // 0..7
    const int tt   = q >> 2;
    const int eh   = (q >> 1) & 1;
    const int kh   = q & 1;
    const int t0   = blockIdx.x * TPB;

    auto stage = [&](int buf, int kb) {     // kb in elements
        char* base = smem + buf * 32768;
        if (q < 4) {                        // X [64 rows][256 B]
#pragma unroll
            for (int j = 0; j < 4; ++j) {
                const int r  = 16 * q + 4 * j + (lane >> 4);
                const int cb = (lane & 15) * 16;
                const int sw = cb ^ ((r & 7) << 4);
                gload16(X + (size_t)(t0 + r) * HIDDEN + kb + (sw >> 2),
                        base + (16 * q + 4 * j) * 256);
            }
        } else if (q < 6) {                 // Whi [64 rows][128 B]
#pragma unroll
            for (int j = 0; j < 4; ++j) {
                const int r  = (q - 4) * 32 + 8 * j + (lane >> 3);
                const int cb = (lane & 7) * 16;
                const int sw = cb ^ ((r & 7) << 4);
                gload16(Whi + (size_t)r * HIDDEN + kb + (sw >> 1),
                        base + 16384 + ((q - 4) * 32 + 8 * j) * 128);
            }
        } else {                            // Wlo [64 rows][128 B]
#pragma unroll
            for (int j = 0; j < 4; ++j) {
                const int r  = (q - 6) * 32 + 8 * j + (lane >> 3);
                const int cb = (lane & 7) * 16;
                const int sw = cb ^ ((r & 7) << 4);
                gload16(Wlo + (size_t)r * HIDDEN + kb + (sw >> 1),
                        base + 24576 + ((q - 6) * 32 + 8 * j) * 128);
            }
        }
    };

    floatx4 acc00 = {0.f,0.f,0.f,0.f}, acc01 = {0.f,0.f,0.f,0.f};
    floatx4 acc10 = {0.f,0.f,0.f,0.f}, acc11 = {0.f,0.f,0.f,0.f};

    auto compute = [&](int buf) {
        const char* bb = smem + buf * 32768;
        // A fragments: 2 token sub-tiles, ks = kh
        short8 ah[2], al[2];
#pragma unroll
        for (int tsub = 0; tsub < 2; ++tsub) {
            const int row = tt * 32 + tsub * 16 + (lane & 15);
            const int swz = (row & 7) << 4;
            const int ab0 = kh * 128 + (lane >> 4) * 32;
            const float4 xa = *reinterpret_cast<const float4*>(bb + row * 256 + ((ab0     ) ^ swz));
            const float4 xc = *reinterpret_cast<const float4*>(bb + row * 256 + ((ab0 + 16) ^ swz));
            unsigned int xu[8] = {
                __builtin_bit_cast(unsigned int, xa.x), __builtin_bit_cast(unsigned int, xa.y),
                __builtin_bit_cast(unsigned int, xa.z), __builtin_bit_cast(unsigned int, xa.w),
                __builtin_bit_cast(unsigned int, xc.x), __builtin_bit_cast(unsigned int, xc.y),
                __builtin_bit_cast(unsigned int, xc.z), __builtin_bit_cast(unsigned int, xc.w)};
            unsigned int hw[4], lw[4];
#pragma unroll
            for (int p = 0; p < 4; ++p) {
                unsigned int u0 = xu[2 * p], u1 = xu[2 * p + 1];
                hw[p] = __builtin_amdgcn_perm(u1, u0, 0x07060302u);  // hi16(u1):hi16(u0)
                float d0 = __builtin_bit_cast(float, u0) - __builtin_bit_cast(float, u0 & 0xFFFF0000u);
                float d1 = __builtin_bit_cast(float, u1) - __builtin_bit_cast(float, u1 & 0xFFFF0000u);
                lw[p] = __builtin_amdgcn_perm(__builtin_bit_cast(unsigned int, d1),
                                              __builtin_bit_cast(unsigned int, d0), 0x07060302u);
            }
            uint4v hv = {hw[0], hw[1], hw[2], hw[3]};
            uint4v lv = {lw[0], lw[1], lw[2], lw[3]};
            ah[tsub] = __builtin_bit_cast(short8, hv);
            al[tsub] = __builtin_bit_cast(short8, lv);
        }
        // B fragments (2 expert sub-tiles) + 3-term split MFMA, acc-interleaved
#pragma unroll
        for (int ei = 0; ei < 2; ++ei) {
            const int erow = eh * 32 + ei * 16 + (lane & 15);
            const int esw  = (erow & 7) << 4;
            const int bb0  = kh * 64 + (lane >> 4) * 16;
            const short8 bhf = *reinterpret_cast<const short8*>(bb + 16384 + erow * 128 + (bb0 ^ esw));
            const short8 blf = *reinterpret_cast<const short8*>(bb + 24576 + erow * 128 + (bb0 ^ esw));
            if (ei == 0) {
                acc00 = __builtin_amdgcn_mfma_f32_16x16x32_bf16(ah[0], bhf, acc00, 0, 0, 0);
                acc10 = __builtin_amdgcn_mfma_f32_16x16x32_bf16(ah[1], bhf, acc10, 0, 0, 0);
                acc00 = __builtin_amdgcn_mfma_f32_16x16x32_bf16(ah[0], blf, acc00, 0, 0, 0);
                acc10 = __builtin_amdgcn_mfma_f32_16x16x32_bf16(ah[1], blf, acc10, 0, 0, 0);
                acc00 = __builtin_amdgcn_mfma_f32_16x16x32_bf16(al[0], bhf, acc00, 0, 0, 0);
                acc10 = __builtin_amdgcn_mfma_f32_16x16x32_bf16(al[1], bhf, acc10, 0, 0, 0);
            } else {
                acc01 = __builtin_amdgcn_mfma_f32_16x16x32_bf16(ah[0], bhf, acc01, 0, 0, 0);
                acc11 = __builtin_amdgcn_mfma_f32_16x16x32_bf16(ah[1], bhf, acc11, 0, 0, 0);
                acc01 = __builtin_amdgcn_mfma_f32_16x16x32_bf16(ah[0], blf, acc01, 0, 0, 0);
                acc11 = __builtin_amdgcn_mfma_f32_16x16x32_bf16(ah[1], blf, acc11, 0, 0, 0);
                acc01 = __builtin_amdgcn_mfma_f32_16x16x32_bf16(al[0], bhf, acc01, 0, 0, 0);
                acc11 = __builtin_amdgcn_mfma_f32_16x16x32_bf16(al[1], bhf, acc11, 0, 0, 0);
            }
        }
    };

    // prologue: 2 chunks in flight
    stage(0, 0);
    stage(1, BK);

#pragma unroll 1
    for (int c = 0; c < NCHUNK - 1; ++c) {
        asm volatile("s_waitcnt vmcnt(4)\n\ts_barrier" ::: "memory");
        __builtin_amdgcn_sched_barrier(0);
        if (c + 2 < NCHUNK) stage((c + 2) % 3, (c + 2) * BK);
        compute(c % 3);
    }
    asm volatile("s_waitcnt vmcnt(0)\n\ts_barrier" ::: "memory");
    __builtin_amdgcn_sched_barrier(0);
    compute((NCHUNK - 1) % 3);

    __syncthreads();
    // D layout (verified r4-r7): col = lane&15 (expert), row = (lane>>4)*4+r (token)
    // 2-way kh reduce + tile assembly in LDS overlay [64][68]
    float* accs = reinterpret_cast<float*>(smem);
    {
        const int rbase = tt * 32 + (lane >> 4) * 4;
        const int cbase = eh * 32 + (lane & 15);
        if (kh == 0) {
#pragma unroll
            for (int r = 0; r < 4; ++r) {
                accs[(rbase +      r) * 68 + cbase     ] = acc00[r];
                accs[(rbase +      r) * 68 + cbase + 16] = acc01[r];
                accs[(rbase + 16 + r) * 68 + cbase     ] = acc10[r];
                accs[(rbase + 16 + r) * 68 + cbase + 16] = acc11[r];
            }
        }
        __syncthreads();
        if (kh == 1) {
#pragma unroll
            for (int r = 0; r < 4; ++r) {
                accs[(rbase +      r) * 68 + cbase     ] += acc00[r];
                accs[(rbase +      r) * 68 + cbase + 16] += acc01[r];
                accs[(rbase + 16 + r) * 68 + cbase     ] += acc10[r];
                accs[(rbase + 16 + r) * 68 + cbase + 16] += acc11[r];
            }
        }
        __syncthreads();
    }

    // epilogue: wave q handles token rows 8q..8q+7; lane = expert
    float* out_w = out;
    float* out_i = out + (size_t)T * TOPK;
#pragma unroll 1
    for (int m = 0; m < 8; ++m) {
        const int row = q * 8 + m;
        const int t = t0 + row;
        float lg = accs[row * 68 + lane];
        float v = 30.0f * tanhf(lg * (1.0f / 30.0f));
        float vcur = v, vmax0 = 0.f, my_e = 0.f, sum = 0.f, prev = 0.f;
        int   my_i = 0;
        bool  ambig = false;
#pragma unroll 1
        for (int k = 0; k < TOPK + 1; ++k) {   // ranks 1..9 with margin check
            float bv = vcur;
            int   bi = lane;
#pragma unroll
            for (int s = 32; s >= 1; s >>= 1) {
                float ov = __shfl_xor(bv, s);
                int   oi = __shfl_xor(bi, s);
                if (ov > bv || (ov == bv && oi < bi)) { bv = ov; bi = oi; }
            }
            if (k == 0) vmax0 = bv;
            else        ambig |= (prev - bv < MARGIN);
            prev = bv;
            if (k < TOPK) {
                float e = __expf(bv - vmax0);
                sum += e;
                if (lane == k) { my_e = e; my_i = bi; }
                if (lane == bi) vcur = -INFINITY;
            }
        }
        if (!ambig) {
            if (lane < TOPK) {
                out_w[(size_t)t * TOPK + lane] = my_e / sum;
                out_i[(size_t)t * TOPK + lane] = (float)my_i;
            }
        } else if (lane == 0) {
            redo_list[atomicAdd(redo_cnt, 1)] = t;
        }
    }
}

// ---------------- pass 2: exact f64 redo of ambiguous tokens ---------------
__global__ __launch_bounds__(256, 2)
void gate_redo(const float* __restrict__ X, const float* __restrict__ W,
               float* __restrict__ out,
               const int* __restrict__ redo_cnt, const int* __restrict__ redo_list,
               int T) {
    __shared__ double lgs[64];
    const int lane = threadIdx.x & 63;
    const int q    = threadIdx.x >> 6;
    const int n    = *redo_cnt;
    float* out_w = out;
    float* out_i = out + (size_t)T * TOPK;

    for (int i = blockIdx.x; i < n; i += gridDim.x) {
        const int t = redo_list[i];
        const float* xr = X + (size_t)t * HIDDEN;
#pragma unroll 1
        for (int j = 0; j < 16; ++j) {
            const int e = q * 16 + j;
            const float* wr = W + (size_t)e * HIDDEN;
            double s = 0.0;
#pragma unroll 2
            for (int k = lane * 4; k < HIDDEN; k += 256) {
                float4 wv = *reinterpret_cast<const float4*>(wr + k);
                float4 xv = *reinterpret_cast<const float4*>(xr + k);
                s = fma((double)xv.x, (double)wv.x, s);
                s = fma((double)xv.y, (double)wv.y, s);
                s = fma((double)xv.z, (double)wv.z, s);
                s = fma((double)xv.w, (double)wv.w, s);
            }
#pragma unroll
            for (int sft = 32; sft >= 1; sft >>= 1) s += __shfl_xor(s, sft);
            if (lane == 0) lgs[e] = s;
        }
        __syncthreads();
        if (q == 0) {
            double vv = 30.0 * tanh(lgs[lane] * (1.0 / 30.0));
            double dmax0 = 0.0, dmy_e = 0.0, dsum = 0.0;
            int    dmy_i = 0;
#pragma unroll 1
            for (int k = 0; k < TOPK; ++k) {
                double bv = vv;
                int    bi = lane;
#pragma unroll
                for (int s = 32; s >= 1; s >>= 1) {
                    double ov = __shfl_xor(bv, s);
                    int    oi = __shfl_xor(bi, s);
                    if (ov > bv || (ov == bv && oi < bi)) { bv = ov; bi = oi; }
                }
                if (k == 0) dmax0 = bv;
                double e = exp(bv - dmax0);
                dsum += e;
                if (lane == k) { dmy_e = e; dmy_i = bi; }
                if (lane == bi) vv = -HUGE_VAL;
            }
            if (lane < TOPK) {
                out_w[(size_t)t * TOPK + lane] = (float)(dmy_e / dsum);
                out_i[(size_t)t * TOPK + lane] = (float)dmy_i;
            }
        }
        __syncthreads();
    }
}

// ---------------- fallback (round-3 proven) if ws too small ----------------
#define F_HC 64
#define F_LDS_STRIDE 68
#define F_TPW 4
#define F_TPB 16

__global__ __launch_bounds__(256, 4)
void moe_gate_fallback(const float* __restrict__ X, const float* __restrict__ W,
                       float* __restrict__ out, int T) {
    __shared__ float wlds[NEXP * F_LDS_STRIDE];
    const int tid  = threadIdx.x;
    const int lane = tid & 63;
    const int wid  = tid >> 6;
    const int t0   = blockIdx.x * F_TPB + wid * F_TPW;
    double accd[F_TPW];
#pragma unroll
    for (int m = 0; m < F_TPW; ++m) accd[m] = 0.0;
    for (int hb = 0; hb < HIDDEN; hb += F_HC) {
        __syncthreads();
#pragma unroll
        for (int k = 0; k < 4; ++k) {
            int f = tid + k * 256, e = f >> 4, c4 = f & 15;
            const float4 wv = *reinterpret_cast<const float4*>(W + e * HIDDEN + hb + c4 * 4);
            *reinterpret_cast<float4*>(&wlds[e * F_LDS_STRIDE + c4 * 4]) = wv;
        }
        __syncthreads();
        float accf[F_TPW];
#pragma unroll
        for (int m = 0; m < F_TPW; ++m) accf[m] = 0.f;
#pragma unroll 4
        for (int h4 = 0; h4 < F_HC / 4; ++h4) {
            const float4 wv = *reinterpret_cast<const float4*>(&wlds[lane * F_LDS_STRIDE + h4 * 4]);
#pragma unroll
            for (int m = 0; m < F_TPW; ++m) {
                const float4 xv = *reinterpret_cast<const float4*>(
                    X + (size_t)(t0 + m) * HIDDEN + hb + h4 * 4);
                accf[m] = fmaf(xv.x, wv.x, accf[m]);
                accf[m] = fmaf(xv.y, wv.y, accf[m]);
                accf[m] = fmaf(xv.z, wv.z, accf[m]);
                accf[m] = fmaf(xv.w, wv.w, accf[m]);
            }
        }
#pragma unroll
        for (int m = 0; m < F_TPW; ++m) accd[m] += (double)accf[m];
    }
    float* out_w = out;
    float* out_i = out + (size_t)T * TOPK;
#pragma unroll 1
    for (int m = 0; m < F_TPW; ++m) {
        const int t = t0 + m;
        double vv = 30.0 * tanh(accd[m] * (1.0 / 30.0));
        double dmax0 = 0.0, dmy_e = 0.0, dsum = 0.0;
        int dmy_i = 0;
#pragma unroll 1
        for (int k = 0; k < TOPK; ++k) {
            double bv = vv; int bi = lane;
#pragma unroll
            for (int s = 32; s >= 1; s >>= 1) {
                double ov = __shfl_xor(bv, s);
                int    oi = __shfl_xor(bi, s);
                if (ov > bv || (ov == bv && oi < bi)) { bv = ov; bi = oi; }
            }
            if (k == 0) dmax0 = bv;
            double e = exp(bv - dmax0);
            dsum += e;
            if (lane == k) { dmy_e = e; dmy_i = bi; }
            if (lane == bi) vv = -HUGE_VAL;
        }
        if (lane < TOPK) {
            out_w[(size_t)t * TOPK + lane] = (float)(dmy_e / dsum);
            out_i[(size_t)t * TOPK + lane] = (float)dmy_i;
        }
    }
}

extern "C" void kernel_launch(void* const* d_in, const int* in_sizes, int n_in,
                              void* d_out, int out_size, void* d_ws, size_t ws_size,
                              hipStream_t stream) {
    const float* X = (const float*)d_in[0];     // [4,4096,4096] fp32
    const float* W = (const float*)d_in[1];     // [64,4096] fp32
    float* out = (float*)d_out;
    const int T = in_sizes[0] / HIDDEN;         // 16384

    if (ws_size < WS_NEED) {
        hipLaunchKernelGGL(moe_gate_fallback, dim3(T / F_TPB), dim3(256), 0, stream, X, W, out, T);
        return;
    }
    char* ws = (char*)d_ws;
    int* cnt  = (int*)ws;
    int* list = (int*)(ws + WS_LIST_OFF);
    unsigned short* Whi = (unsigned short*)(ws + WS_WHI_OFF);
    unsigned short* Wlo = (unsigned short*)(ws + WS_WLO_OFF);

    hipLaunchKernelGGL(wconv_kernel, dim3(256), dim3(256), 0, stream, W, Whi, Wlo, cnt);
    hipLaunchKernelGGL(gate_mfma, dim3(T / TPB), dim3(512), 0, stream,
                       X, Whi, Wlo, out, cnt, list, T);
    hipLaunchKernelGGL(gate_redo, dim3(256), dim3(256), 0, stream,
                       X, W, out, cnt, list, T);
}